// Round 4
// baseline (1262.304 us; speedup 1.0000x reference)
//
#include <hip/hip_runtime.h>
#include <hip/hip_fp16.h>

// SparseConvTransposeBlock, round 12: A/B round.
// Real output path = proven R6 pipeline (k1_fp16 fp16-atomic scatter, 225us)
// + NEW fused stats+BN+ReLU epilogue (k23_fused, ticket-barrier) replacing
// k2+k3 (saves a launch gap + ~10-20us).
// Piggyback experiment (scrap workspace, after real path): dechained binned
// k_main_x — no __shfl in the accumulate (row targets loaded as dwordx4
// straight from entries), so ds_adds issue with NO lgkm waits in the loop.
// Discriminates: [bpermute->lgkmcnt(0) serial chain] vs [LDS-atomic
// throughput] as the cause of R9/R11's 820us (identical despite ds_add fix).

#define C_DIM 64
#define LDS_STRIDE 72   // bf16 elems per Wt row: 64 + 8 pad
#define ROW_STRIDE 68   // fp32 elems per scratch row: 64 + 4 pad

#define BUCKET_BITS 7                 // 128 output rows per bucket
#define BUCKET_ROWS (1 << BUCKET_BITS)
#define BIN_CAP 128                   // entries per (k,bucket) bin
#define ACC_STRIDE 65                 // fp32 LDS acc row stride

typedef __bf16 bf16_t;
typedef bf16_t bf16x4 __attribute__((ext_vector_type(4)));
typedef bf16_t bf16x8 __attribute__((ext_vector_type(8)));
typedef float floatx4 __attribute__((ext_vector_type(4)));

__device__ __forceinline__ void lds_add_f32(float* p, float v)
{
    unsigned off = (unsigned)(unsigned long long)p;
    asm volatile("ds_add_f32 %0, %1" : : "v"(off), "v"(v));
}

// ---------------------------------------------- features f32 -> bf16 table
__global__ __launch_bounds__(256)
void k_fprep(const float* __restrict__ f, bf16_t* __restrict__ fb, int total4)
{
    int i = blockIdx.x * 256 + threadIdx.x;
    if (i < total4) {
        float4 v = ((const float4*)f)[i];
        bf16x4 o;
        o[0] = (bf16_t)v.x; o[1] = (bf16_t)v.y;
        o[2] = (bf16_t)v.z; o[3] = (bf16_t)v.w;
        ((bf16x4*)fb)[i] = o;
    }
}

// ================= R6 main kernel (proven, 225us) ===========================
__global__ __launch_bounds__(256)
void k1_fp16(const float* __restrict__ features,
             const bf16_t* __restrict__ fbf16,
             const float* __restrict__ weight,
             const int* __restrict__ pairs_in,
             const int* __restrict__ pairs_out,
             __half* __restrict__ acc,
             int P, int rows_per_block, int use_bf16)
{
    __shared__ bf16_t Wt[C_DIM * LDS_STRIDE];
    __shared__ float  scratch[4][16 * ROW_STRIDE];

    const int k   = blockIdx.y;
    const int tid = threadIdx.x;

    const float* Wk = weight + (size_t)k * C_DIM * C_DIM;
    for (int i = tid; i < C_DIM * C_DIM; i += 256) {
        int c = i >> 6, d = i & 63;
        Wt[d * LDS_STRIDE + c] = (bf16_t)Wk[i];
    }
    __syncthreads();

    const int wave = tid >> 6;
    const int lane = tid & 63;
    const int quad = lane >> 4;
    const int col  = lane & 15;
    const int sub  = lane >> 5;
    const int c2   = lane & 31;
    float* ls = &scratch[wave][0];

    bf16x8 bfrag[2][4];
    #pragma unroll
    for (int ks = 0; ks < 2; ++ks)
        #pragma unroll
        for (int nt = 0; nt < 4; ++nt)
            bfrag[ks][nt] =
                *(const bf16x8*)&Wt[(col + 16 * nt) * LDS_STRIDE + quad * 8 + 32 * ks];

    const int* __restrict__ pin  = pairs_in  + (size_t)k * P;
    const int* __restrict__ pout = pairs_out + (size_t)k * P;

    const int p0   = blockIdx.x * rows_per_block;
    const int pend = min(p0 + rows_per_block, P);

    for (int base = p0 + wave * 16; base < pend; base += 64) {
        int prow    = base + col;
        int clamped = (prow < pend) ? prow : (pend - 1);
        int in_idx  = pin[clamped];
        int out_idx = pout[clamped];

        bf16x8 a0, a1;
        if (use_bf16) {
            const bf16_t* src = fbf16 + (size_t)in_idx * C_DIM + quad * 8;
            a0 = *(const bf16x8*)(src);
            a1 = *(const bf16x8*)(src + 32);
        } else {
            const float* src = features + (size_t)in_idx * C_DIM + quad * 8;
            float4 f0 = *(const float4*)(src);
            float4 f1 = *(const float4*)(src + 4);
            float4 f2 = *(const float4*)(src + 32);
            float4 f3 = *(const float4*)(src + 36);
            a0[0] = (bf16_t)f0.x; a0[1] = (bf16_t)f0.y; a0[2] = (bf16_t)f0.z; a0[3] = (bf16_t)f0.w;
            a0[4] = (bf16_t)f1.x; a0[5] = (bf16_t)f1.y; a0[6] = (bf16_t)f1.z; a0[7] = (bf16_t)f1.w;
            a1[0] = (bf16_t)f2.x; a1[1] = (bf16_t)f2.y; a1[2] = (bf16_t)f2.z; a1[3] = (bf16_t)f2.w;
            a1[4] = (bf16_t)f3.x; a1[5] = (bf16_t)f3.y; a1[6] = (bf16_t)f3.z; a1[7] = (bf16_t)f3.w;
        }

        floatx4 acc0 = {0.f, 0.f, 0.f, 0.f};
        floatx4 acc1 = {0.f, 0.f, 0.f, 0.f};
        floatx4 acc2 = {0.f, 0.f, 0.f, 0.f};
        floatx4 acc3 = {0.f, 0.f, 0.f, 0.f};

        acc0 = __builtin_amdgcn_mfma_f32_16x16x32_bf16(a0, bfrag[0][0], acc0, 0, 0, 0);
        acc0 = __builtin_amdgcn_mfma_f32_16x16x32_bf16(a1, bfrag[1][0], acc0, 0, 0, 0);
        acc1 = __builtin_amdgcn_mfma_f32_16x16x32_bf16(a0, bfrag[0][1], acc1, 0, 0, 0);
        acc1 = __builtin_amdgcn_mfma_f32_16x16x32_bf16(a1, bfrag[1][1], acc1, 0, 0, 0);
        acc2 = __builtin_amdgcn_mfma_f32_16x16x32_bf16(a0, bfrag[0][2], acc2, 0, 0, 0);
        acc2 = __builtin_amdgcn_mfma_f32_16x16x32_bf16(a1, bfrag[1][2], acc2, 0, 0, 0);
        acc3 = __builtin_amdgcn_mfma_f32_16x16x32_bf16(a0, bfrag[0][3], acc3, 0, 0, 0);
        acc3 = __builtin_amdgcn_mfma_f32_16x16x32_bf16(a1, bfrag[1][3], acc3, 0, 0, 0);

        #pragma unroll
        for (int r = 0; r < 4; ++r) {
            int m = quad * 4 + r;
            ls[m * ROW_STRIDE + col +  0] = acc0[r];
            ls[m * ROW_STRIDE + col + 16] = acc1[r];
            ls[m * ROW_STRIDE + col + 32] = acc2[r];
            ls[m * ROW_STRIDE + col + 48] = acc3[r];
        }
        asm volatile("s_waitcnt lgkmcnt(0)" ::: "memory");

        #pragma unroll
        for (int m2 = 0; m2 < 8; ++m2) {
            int m = m2 * 2 + sub;
            float2 v = *(const float2*)&ls[m * ROW_STRIDE + 2 * c2];
            __half2 h = __floats2half2_rn(v.x, v.y);
            int g = __shfl(out_idx, m);
            if (base + m < pend)
                unsafeAtomicAdd((__half2*)(acc + (size_t)g * C_DIM + 2 * c2), h);
        }
    }
}

// ---------------- fused stats + ticket barrier + BN/ReLU --------------------
// 256 blocks (<= 256 CUs, tiny footprint -> all resident: no deadlock).
__global__ __launch_bounds__(256)
void k23_fused(const __half* __restrict__ acc, float* __restrict__ out,
               float* __restrict__ sums, int* __restrict__ ticket,
               const float* __restrict__ gamma, const float* __restrict__ beta,
               int n_rows, int nblocks)
{
    const int tid = threadIdx.x;
    const int c8  = tid & 7;
    const int sub = tid >> 3;

    // phase 1: partial per-channel sum / sumsq (same as proven k2_stats_h)
    float s[8] = {0,0,0,0,0,0,0,0}, q[8] = {0,0,0,0,0,0,0,0};
    for (int r = blockIdx.x * 32 + sub; r < n_rows; r += nblocks * 32) {
        float4 v = *(const float4*)&acc[(size_t)r * C_DIM + c8 * 8];
        const __half2* h = (const __half2*)&v;
        #pragma unroll
        for (int j = 0; j < 4; ++j) {
            float x = __half2float(h[j].x), y = __half2float(h[j].y);
            s[2*j]   += x; q[2*j]   += x * x;
            s[2*j+1] += y; q[2*j+1] += y * y;
        }
    }
    __shared__ float red[128];
    if (tid < 128) red[tid] = 0.f;
    __syncthreads();
    #pragma unroll
    for (int j = 0; j < 8; ++j) {
        atomicAdd(&red[c8 * 8 + j], s[j]);
        atomicAdd(&red[64 + c8 * 8 + j], q[j]);
    }
    __syncthreads();
    if (tid < 128) unsafeAtomicAdd(&sums[tid], red[tid]);
    __syncthreads();   // compiler emits vmcnt(0) before barrier -> atomics done

    // ticket barrier (device-scope atomics; spin on one lane)
    if (tid == 0) {
        __threadfence();
        atomicAdd(ticket, 1);
        while (atomicAdd(ticket, 0) < nblocks)
            __builtin_amdgcn_s_sleep(1);
    }
    __syncthreads();

    // snapshot sums via atomic-reads (coherence point, XCD-safe)
    __shared__ float snap[128];
    if (tid < 128) snap[tid] = unsafeAtomicAdd(&sums[tid], 0.0f);
    __syncthreads();

    float inv_n = 1.0f / (float)n_rows;
    float sc[8], sh[8];
    #pragma unroll
    for (int j = 0; j < 8; ++j) {
        int ch    = c8 * 8 + j;
        float m   = snap[ch] * inv_n;
        float var = snap[64 + ch] * inv_n - m * m;
        float inv = rsqrtf(var + 1e-5f);
        float g   = gamma[ch] * inv;
        sc[j] = g;
        sh[j] = beta[ch] - m * g;
    }

    // phase 2: normalize + ReLU (same as proven k3_bn_relu_h)
    size_t total = (size_t)n_rows * 8;   // halfx8 octets
    for (size_t i = blockIdx.x * 256 + tid; i < total; i += (size_t)nblocks * 256) {
        float4 v = ((const float4*)acc)[i];
        const __half2* h = (const __half2*)&v;
        float4 o0, o1;
        o0.x = fmaxf(__half2float(h[0].x) * sc[0] + sh[0], 0.f);
        o0.y = fmaxf(__half2float(h[0].y) * sc[1] + sh[1], 0.f);
        o0.z = fmaxf(__half2float(h[1].x) * sc[2] + sh[2], 0.f);
        o0.w = fmaxf(__half2float(h[1].y) * sc[3] + sh[3], 0.f);
        o1.x = fmaxf(__half2float(h[2].x) * sc[4] + sh[4], 0.f);
        o1.y = fmaxf(__half2float(h[2].y) * sc[5] + sh[5], 0.f);
        o1.z = fmaxf(__half2float(h[3].x) * sc[6] + sh[6], 0.f);
        o1.w = fmaxf(__half2float(h[3].y) * sc[7] + sh[7], 0.f);
        ((float4*)out)[2 * i]     = o0;
        ((float4*)out)[2 * i + 1] = o1;
    }
}

// ================= piggyback experiment (scrap output) ======================
__global__ __launch_bounds__(64)
void w_prep(const float* __restrict__ w, bf16_t* __restrict__ wp)
{
    int k = blockIdx.x;
    int lane = threadIdx.x;
    int quad = lane >> 4, col = lane & 15;
    const float* Wk = w + (size_t)k * C_DIM * C_DIM;
    bf16_t* dst = wp + ((size_t)(k * 64 + lane)) * 64;
    #pragma unroll
    for (int ks = 0; ks < 2; ++ks)
        #pragma unroll
        for (int nt = 0; nt < 4; ++nt)
            #pragma unroll
            for (int j = 0; j < 8; ++j)
                dst[(ks * 4 + nt) * 8 + j] =
                    (bf16_t)Wk[(quad * 8 + j + 32 * ks) * C_DIM + col + 16 * nt];
}

__global__ __launch_bounds__(256)
void b_reorder(const int* __restrict__ pin, const int* __restrict__ pout,
               int* __restrict__ cnt, unsigned* __restrict__ entries,
               int P, int NB)
{
    int k = blockIdx.y;
    int i = blockIdx.x * 256 + threadIdx.x;
    if (i >= P) return;
    int o  = pout[(size_t)k * P + i];
    int in = pin [(size_t)k * P + i];
    int bin = k * NB + (o >> BUCKET_BITS);
    int pos = atomicAdd(&cnt[bin], 1);
    if (pos < BIN_CAP)
        entries[((size_t)bin << BUCKET_BITS) + pos] =
            (unsigned)in | ((unsigned)(o & (BUCKET_ROWS - 1)) << 17);
}

// Dechained k_main: row targets come from a dwordx4 load of the entries
// array (NOT a __shfl of a register), so the 16 ds_adds per tile issue
// back-to-back with no lgkm waits anywhere in the loop.
__global__ __launch_bounds__(512)
void k_main_x(const bf16_t* __restrict__ fb, const bf16_t* __restrict__ wp,
              const int* __restrict__ cnt, const unsigned* __restrict__ entries,
              float* __restrict__ outx, float* __restrict__ sumsx,
              int NB, int n_out, int K3)
{
    __shared__ float accs[BUCKET_ROWS * ACC_STRIDE];

    const int tid  = threadIdx.x;
    const int wave = tid >> 6;
    const int lane = tid & 63;
    const int quad = lane >> 4;
    const int col  = lane & 15;
    const int b    = blockIdx.x;

    for (int i = tid; i < BUCKET_ROWS * ACC_STRIDE; i += 512) accs[i] = 0.f;
    __syncthreads();

    int tctr = 0;
    for (int k = 0; k < K3; ++k) {
        int bin = k * NB + b;
        int n = min(cnt[bin], BIN_CAP);
        int ntile = (n + 15) >> 4;
        if (ntile == 0) continue;
        int rel = wave - tctr; rel = ((rel % 8) + 8) % 8;
        tctr += ntile;
        if (rel >= ntile) continue;

        const bf16_t* wpk = wp + ((size_t)(k * 64 + lane)) * 64;
        bf16x8 bf[2][4];
        #pragma unroll
        for (int ks = 0; ks < 2; ++ks)
            #pragma unroll
            for (int nt = 0; nt < 4; ++nt)
                bf[ks][nt] = *(const bf16x8*)(wpk + (ks * 4 + nt) * 8);

        const unsigned* ebase = entries + ((size_t)bin << BUCKET_BITS);
        for (int t = rel; t < ntile; t += 8) {
            int base = t * 16;
            // own entry (gather index), and this quad's 4 row targets
            unsigned eown = ebase[min(base + col, n - 1)];
            uint4 e4 = *(const uint4*)(ebase + base + quad * 4);
            int in = (int)(eown & 0x1FFFFu);

            const bf16_t* src = fb + ((size_t)in << 6) + quad * 8;
            bf16x8 a0 = *(const bf16x8*)(src);
            bf16x8 a1 = *(const bf16x8*)(src + 32);

            int rr0 = (base + quad * 4 + 0 < n) ? (int)((e4.x >> 17) & 127u) : -1;
            int rr1 = (base + quad * 4 + 1 < n) ? (int)((e4.y >> 17) & 127u) : -1;
            int rr2 = (base + quad * 4 + 2 < n) ? (int)((e4.z >> 17) & 127u) : -1;
            int rr3 = (base + quad * 4 + 3 < n) ? (int)((e4.w >> 17) & 127u) : -1;

            floatx4 c0 = {0.f,0.f,0.f,0.f}, c1 = {0.f,0.f,0.f,0.f};
            floatx4 c2 = {0.f,0.f,0.f,0.f}, c3 = {0.f,0.f,0.f,0.f};
            c0 = __builtin_amdgcn_mfma_f32_16x16x32_bf16(a0, bf[0][0], c0, 0, 0, 0);
            c0 = __builtin_amdgcn_mfma_f32_16x16x32_bf16(a1, bf[1][0], c0, 0, 0, 0);
            c1 = __builtin_amdgcn_mfma_f32_16x16x32_bf16(a0, bf[0][1], c1, 0, 0, 0);
            c1 = __builtin_amdgcn_mfma_f32_16x16x32_bf16(a1, bf[1][1], c1, 0, 0, 0);
            c2 = __builtin_amdgcn_mfma_f32_16x16x32_bf16(a0, bf[0][2], c2, 0, 0, 0);
            c2 = __builtin_amdgcn_mfma_f32_16x16x32_bf16(a1, bf[1][2], c2, 0, 0, 0);
            c3 = __builtin_amdgcn_mfma_f32_16x16x32_bf16(a0, bf[0][3], c3, 0, 0, 0);
            c3 = __builtin_amdgcn_mfma_f32_16x16x32_bf16(a1, bf[1][3], c3, 0, 0, 0);

            // C[m=quad*4+r][ch] -> LDS row rr_r. No cross-lane ops: all 16
            // ds_adds issue back-to-back, zero lgkm waits in the loop.
            if (rr0 >= 0) {
                float* d = &accs[rr0 * ACC_STRIDE];
                lds_add_f32(d + col, c0[0]); lds_add_f32(d + col + 16, c1[0]);
                lds_add_f32(d + col + 32, c2[0]); lds_add_f32(d + col + 48, c3[0]);
            }
            if (rr1 >= 0) {
                float* d = &accs[rr1 * ACC_STRIDE];
                lds_add_f32(d + col, c0[1]); lds_add_f32(d + col + 16, c1[1]);
                lds_add_f32(d + col + 32, c2[1]); lds_add_f32(d + col + 48, c3[1]);
            }
            if (rr2 >= 0) {
                float* d = &accs[rr2 * ACC_STRIDE];
                lds_add_f32(d + col, c0[2]); lds_add_f32(d + col + 16, c1[2]);
                lds_add_f32(d + col + 32, c2[2]); lds_add_f32(d + col + 48, c3[2]);
            }
            if (rr3 >= 0) {
                float* d = &accs[rr3 * ACC_STRIDE];
                lds_add_f32(d + col, c0[3]); lds_add_f32(d + col + 16, c1[3]);
                lds_add_f32(d + col + 32, c2[3]); lds_add_f32(d + col + 48, c3[3]);
            }
        }
    }
    asm volatile("s_waitcnt lgkmcnt(0)" ::: "memory");
    __syncthreads();

    const int ch  = tid & 63;
    const int sub = tid >> 6;
    const int row0 = b << BUCKET_BITS;
    float s = 0.f, q = 0.f;
    for (int r = sub; r < BUCKET_ROWS; r += 8) {
        int gr = row0 + r;
        if (gr < n_out) {
            float v = accs[r * ACC_STRIDE + ch];
            s += v; q += v * v;
            outx[((size_t)gr << 6) + ch] = v;
        }
    }
    __syncthreads();
    accs[tid] = s; accs[512 + tid] = q;
    __syncthreads();
    if (wave == 0) {
        float ts = 0.f, tq = 0.f;
        #pragma unroll
        for (int w2 = 0; w2 < 8; ++w2) {
            ts += accs[w2 * 64 + ch];
            tq += accs[512 + w2 * 64 + ch];
        }
        unsafeAtomicAdd(&sumsx[ch], ts);
        unsafeAtomicAdd(&sumsx[64 + ch], tq);
    }
}

// ===================== fallback (R1 path, proven) ===========================
__global__ __launch_bounds__(256)
void k1_scatter_gemm(const float* __restrict__ features,
                     const float* __restrict__ weight,
                     const int* __restrict__ pairs_in,
                     const int* __restrict__ pairs_out,
                     float* __restrict__ out,
                     int P, int rows_per_block)
{
    __shared__ bf16_t Wt[C_DIM * LDS_STRIDE];
    const int k   = blockIdx.y;
    const int tid = threadIdx.x;
    const float* Wk = weight + (size_t)k * C_DIM * C_DIM;
    for (int i = tid; i < C_DIM * C_DIM; i += 256) {
        int c = i >> 6, d = i & 63;
        Wt[d * LDS_STRIDE + c] = (bf16_t)Wk[i];
    }
    __syncthreads();
    const int wave = tid >> 6, lane = tid & 63, quad = lane >> 4, col = lane & 15;
    bf16x8 bfrag[2][4];
    #pragma unroll
    for (int ks = 0; ks < 2; ++ks)
        #pragma unroll
        for (int nt = 0; nt < 4; ++nt)
            bfrag[ks][nt] =
                *(const bf16x8*)&Wt[(col + 16 * nt) * LDS_STRIDE + quad * 8 + 32 * ks];
    const int* __restrict__ pin  = pairs_in  + (size_t)k * P;
    const int* __restrict__ pout = pairs_out + (size_t)k * P;
    const int p0   = blockIdx.x * rows_per_block;
    const int pend = min(p0 + rows_per_block, P);
    for (int base = p0 + wave * 16; base < pend; base += 64) {
        int prow    = base + col;
        int clamped = (prow < pend) ? prow : (pend - 1);
        int in_idx  = pin[clamped];
        int out_idx = pout[clamped];
        const float* src = features + (size_t)in_idx * C_DIM + quad * 8;
        float4 f0 = *(const float4*)(src);
        float4 f1 = *(const float4*)(src + 4);
        float4 f2 = *(const float4*)(src + 32);
        float4 f3 = *(const float4*)(src + 36);
        bf16x8 a0, a1;
        a0[0] = (bf16_t)f0.x; a0[1] = (bf16_t)f0.y; a0[2] = (bf16_t)f0.z; a0[3] = (bf16_t)f0.w;
        a0[4] = (bf16_t)f1.x; a0[5] = (bf16_t)f1.y; a0[6] = (bf16_t)f1.z; a0[7] = (bf16_t)f1.w;
        a1[0] = (bf16_t)f2.x; a1[1] = (bf16_t)f2.y; a1[2] = (bf16_t)f2.z; a1[3] = (bf16_t)f2.w;
        a1[4] = (bf16_t)f3.x; a1[5] = (bf16_t)f3.y; a1[6] = (bf16_t)f3.z; a1[7] = (bf16_t)f3.w;
        floatx4 acc0 = {0.f,0.f,0.f,0.f}, acc1 = {0.f,0.f,0.f,0.f};
        floatx4 acc2 = {0.f,0.f,0.f,0.f}, acc3 = {0.f,0.f,0.f,0.f};
        acc0 = __builtin_amdgcn_mfma_f32_16x16x32_bf16(a0, bfrag[0][0], acc0, 0, 0, 0);
        acc0 = __builtin_amdgcn_mfma_f32_16x16x32_bf16(a1, bfrag[1][0], acc0, 0, 0, 0);
        acc1 = __builtin_amdgcn_mfma_f32_16x16x32_bf16(a0, bfrag[0][1], acc1, 0, 0, 0);
        acc1 = __builtin_amdgcn_mfma_f32_16x16x32_bf16(a1, bfrag[1][1], acc1, 0, 0, 0);
        acc2 = __builtin_amdgcn_mfma_f32_16x16x32_bf16(a0, bfrag[0][2], acc2, 0, 0, 0);
        acc2 = __builtin_amdgcn_mfma_f32_16x16x32_bf16(a1, bfrag[1][2], acc2, 0, 0, 0);
        acc3 = __builtin_amdgcn_mfma_f32_16x16x32_bf16(a0, bfrag[0][3], acc3, 0, 0, 0);
        acc3 = __builtin_amdgcn_mfma_f32_16x16x32_bf16(a1, bfrag[1][3], acc3, 0, 0, 0);
        #pragma unroll
        for (int r = 0; r < 4; ++r) {
            int m = quad * 4 + r;
            int g = __shfl(out_idx, m);
            if (base + m < pend) {
                float* dst = out + (size_t)g * C_DIM + col;
                unsafeAtomicAdd(dst +  0, acc0[r]);
                unsafeAtomicAdd(dst + 16, acc1[r]);
                unsafeAtomicAdd(dst + 32, acc2[r]);
                unsafeAtomicAdd(dst + 48, acc3[r]);
            }
        }
    }
}

__global__ __launch_bounds__(256)
void k2_stats(const float* __restrict__ acc, float* __restrict__ sums, int n_rows)
{
    int tid = threadIdx.x;
    int ch  = tid & 63;
    int sub = tid >> 6;
    float s = 0.f, s2 = 0.f;
    for (int r = blockIdx.x * 4 + sub; r < n_rows; r += gridDim.x * 4) {
        float v = acc[(size_t)r * C_DIM + ch];
        s  += v;
        s2 += v * v;
    }
    __shared__ float red[256];
    red[tid] = s;
    __syncthreads();
    if (tid < 64) {
        float t = red[tid] + red[tid + 64] + red[tid + 128] + red[tid + 192];
        atomicAdd(&sums[ch], t);
    }
    __syncthreads();
    red[tid] = s2;
    __syncthreads();
    if (tid < 64) {
        float t = red[tid] + red[tid + 64] + red[tid + 128] + red[tid + 192];
        atomicAdd(&sums[64 + ch], t);
    }
}

__global__ __launch_bounds__(256)
void k3_bn_relu(float* __restrict__ out, const float* __restrict__ sums,
                const float* __restrict__ gamma, const float* __restrict__ beta,
                int n_rows)
{
    int tid = blockIdx.x * 256 + threadIdx.x;
    int ch0 = (tid * 4) & 63;
    float inv_n = 1.0f / (float)n_rows;
    float sc[4], sh[4];
    #pragma unroll
    for (int j = 0; j < 4; ++j) {
        int ch    = ch0 + j;
        float m   = sums[ch] * inv_n;
        float var = sums[64 + ch] * inv_n - m * m;
        float inv = rsqrtf(var + 1e-5f);
        float g   = gamma[ch] * inv;
        sc[j] = g;
        sh[j] = beta[ch] - m * g;
    }
    size_t total = (size_t)n_rows * C_DIM / 4;
    for (size_t i = tid; i < total; i += (size_t)gridDim.x * 256) {
        float4 v = ((const float4*)out)[i];
        v.x = fmaxf(v.x * sc[0] + sh[0], 0.f);
        v.y = fmaxf(v.y * sc[1] + sh[1], 0.f);
        v.z = fmaxf(v.z * sc[2] + sh[2], 0.f);
        v.w = fmaxf(v.w * sc[3] + sh[3], 0.f);
        ((float4*)out)[i] = v;
    }
}

// ============================================================================
extern "C" void kernel_launch(void* const* d_in, const int* in_sizes, int n_in,
                              void* d_out, int out_size, void* d_ws, size_t ws_size,
                              hipStream_t stream)
{
    const float* features  = (const float*)d_in[0];
    const float* weight    = (const float*)d_in[1];
    // d_in[2] = bias (cancels in training-mode BN)
    const float* gamma     = (const float*)d_in[3];
    const float* beta      = (const float*)d_in[4];
    const int*   pairs_in  = (const int*)d_in[5];
    const int*   pairs_out = (const int*)d_in[6];

    const int n_out     = out_size / C_DIM;
    const int n_in_rows = in_sizes[0] / C_DIM;
    const int K3        = in_sizes[1] / (C_DIM * C_DIM);
    const int P         = in_sizes[5] / K3;

    float* out = (float*)d_out;

    // ---------------- R6 path workspace layout ----------------
    // [0,512): sums   [512,516): ticket   1024: fp16 acc   then bf16 fb
    const size_t off_acc = 1024;
    size_t acc_bytes = (size_t)n_out * C_DIM * 2;
    size_t off_fb    = (off_acc + acc_bytes + 255) & ~(size_t)255;
    size_t fb_bytes  = (size_t)n_in_rows * C_DIM * 2;
    size_t need_b    = off_acc + acc_bytes;
    size_t need_a    = off_fb + fb_bytes;

    // ---------------- experiment layout (aliases acc+fb as scrap) ----------
    const int    NB      = (n_out + BUCKET_ROWS - 1) >> BUCKET_BITS;
    const size_t NBINS   = (size_t)K3 * NB;
    const size_t off_scr = 1024;                                   // scrap fp32 out
    size_t off_se  = (off_scr + (size_t)n_out * C_DIM * 4 + 255) & ~(size_t)255;
    size_t off_cnt = off_se + 512;
    size_t off_wp  = (off_cnt + NBINS * 4 + 255) & ~(size_t)255;
    size_t off_en  = (off_wp + (size_t)K3 * C_DIM * C_DIM * 2 + 255) & ~(size_t)255;
    size_t need_x  = off_en + NBINS * BIN_CAP * 4;

    const int rows_per_block = 512;
    dim3 g1((P + rows_per_block - 1) / rows_per_block, K3);

    if (ws_size >= need_b) {
        const int use_bf16 = (ws_size >= need_a) ? 1 : 0;

        float*  sums   = (float*)d_ws;
        int*    ticket = (int*)((char*)d_ws + 512);
        __half* acc    = (__half*)((char*)d_ws + off_acc);
        bf16_t* fbf16  = (bf16_t*)((char*)d_ws + off_fb);

        // fused clear: sums + ticket + fp16 accumulator
        hipMemsetAsync(d_ws, 0, off_acc + acc_bytes, stream);
        if (use_bf16)
            k_fprep<<<(n_in_rows * 16 + 255) / 256, 256, 0, stream>>>(
                features, fbf16, n_in_rows * 16);

        k1_fp16<<<g1, 256, 0, stream>>>(features, fbf16, weight, pairs_in,
                                        pairs_out, acc, P, rows_per_block,
                                        use_bf16);

        k23_fused<<<dim3(256), 256, 0, stream>>>(acc, out, sums, ticket,
                                                 gamma, beta, n_out, 256);

        // -------- piggyback experiment: runs AFTER the real path; writes
        // only workspace (scrap aliases the now-dead acc+fb regions). ------
        if (use_bf16 && ws_size >= need_x && n_in_rows <= (1 << 17)) {
            float*    scrap = (float*)((char*)d_ws + off_scr);
            float*    sumsx = (float*)((char*)d_ws + off_se);
            int*      cnt   = (int*)((char*)d_ws + off_cnt);
            bf16_t*   wpb   = (bf16_t*)((char*)d_ws + off_wp);
            unsigned* ent   = (unsigned*)((char*)d_ws + off_en);

            hipMemsetAsync((char*)d_ws + off_se, 0,
                           off_cnt + NBINS * 4 - off_se, stream);
            w_prep<<<K3, 64, 0, stream>>>(weight, wpb);
            dim3 gr((P + 255) / 256, K3);
            b_reorder<<<gr, 256, 0, stream>>>(pairs_in, pairs_out, cnt, ent,
                                              P, NB);
            k_main_x<<<NB, 512, 0, stream>>>(fbf16, wpb, cnt, ent, scrap,
                                             sumsx, NB, n_out, K3);
        }
    } else {
        // fallback: proven R1 path
        hipMemsetAsync(d_out, 0, (size_t)out_size * sizeof(float), stream);
        hipMemsetAsync(d_ws, 0, 512, stream);

        k1_scatter_gemm<<<g1, 256, 0, stream>>>(features, weight, pairs_in,
                                                pairs_out, out, P, rows_per_block);
        k2_stats<<<dim3(1024), 256, 0, stream>>>((float*)out, (float*)d_ws, n_out);
        k3_bn_relu<<<dim3(1024), 256, 0, stream>>>(out, (float*)d_ws, gamma,
                                                   beta, n_out);
    }
}

// Round 5
// 486.437 us; speedup vs baseline: 2.5950x; 2.5950x over previous
//
#include <hip/hip_runtime.h>
#include <hip/hip_fp16.h>

// SparseConvTransposeBlock, round 13: bucket-clustered global fp16 atomics.
//
// R12's A/B verdict: LDS fp32 atomics are the wall (~3.6 cy/lane-op; three
// structurally different kernels all pinned at 820us). LDS accumulation
// abandoned. Instead: keep the (k, 128-row-bucket) binning (proven R9/R11)
// and let block b process ALL k-bins of bucket b with R6's proven fp16
// pk-atomic epilogue. All ~10.8 contributions per output row now issue from
// ONE CU within microseconds -> L2 merges them -> each 128B row flushes
// once: WRITE 270MB -> ~26MB. Gather/MFMA/epilogue verbatim R6.
//
// Decision variable: k_bucket WRITE_SIZE (~30MB = merge works; ~270MB =
// atomics write through unmerged -> revert to plain R6 next round).
//
// Fallbacks: R6 fp16-atomic path, then R1 fp32 path.

#define C_DIM 64
#define LDS_STRIDE 72   // bf16 elems per Wt row: 64 + 8 pad
#define ROW_STRIDE 68   // fp32 elems per scratch row: 64 + 4 pad

#define BUCKET_BITS 7                 // 128 output rows per bucket
#define BUCKET_ROWS (1 << BUCKET_BITS)
#define BIN_CAP 128                   // entries per (k,bucket) bin

typedef __bf16 bf16_t;
typedef bf16_t bf16x4 __attribute__((ext_vector_type(4)));
typedef bf16_t bf16x8 __attribute__((ext_vector_type(8)));
typedef float floatx4 __attribute__((ext_vector_type(4)));

// ---------------------------------------------- features f32 -> bf16 table
__global__ __launch_bounds__(256)
void k_fprep(const float* __restrict__ f, bf16_t* __restrict__ fb, int total4)
{
    int i = blockIdx.x * 256 + threadIdx.x;
    if (i < total4) {
        float4 v = ((const float4*)f)[i];
        bf16x4 o;
        o[0] = (bf16_t)v.x; o[1] = (bf16_t)v.y;
        o[2] = (bf16_t)v.z; o[3] = (bf16_t)v.w;
        ((bf16x4*)fb)[i] = o;
    }
}

// ------------- W -> per-lane MFMA B-fragment layout (bf16), 128B per lane.
// wp[k][lane][(ks*4+nt)*8 + j] = W[k][quad*8+j+32*ks][col+16*nt]
// (proven correct in R9/R11: binned path passed with this layout)
__global__ __launch_bounds__(64)
void w_prep(const float* __restrict__ w, bf16_t* __restrict__ wp)
{
    int k = blockIdx.x;
    int lane = threadIdx.x;
    int quad = lane >> 4, col = lane & 15;
    const float* Wk = w + (size_t)k * C_DIM * C_DIM;
    bf16_t* dst = wp + ((size_t)(k * 64 + lane)) * 64;
    #pragma unroll
    for (int ks = 0; ks < 2; ++ks)
        #pragma unroll
        for (int nt = 0; nt < 4; ++nt)
            #pragma unroll
            for (int j = 0; j < 8; ++j)
                dst[(ks * 4 + nt) * 8 + j] =
                    (bf16_t)Wk[(quad * 8 + j + 32 * ks) * C_DIM + col + 16 * nt];
}

// ------------- binning: entry = in_idx[16:0] | row_local[6:0]<<17 into
// fixed-capacity bins indexed (k, out_idx>>7). cnt[] pre-zeroed.
// (proven correct in R9/R11)
__global__ __launch_bounds__(256)
void b_reorder(const int* __restrict__ pin, const int* __restrict__ pout,
               int* __restrict__ cnt, unsigned* __restrict__ entries,
               int P, int NB)
{
    int k = blockIdx.y;
    int i = blockIdx.x * 256 + threadIdx.x;
    if (i >= P) return;
    int o  = pout[(size_t)k * P + i];
    int in = pin [(size_t)k * P + i];
    int bin = k * NB + (o >> BUCKET_BITS);
    int pos = atomicAdd(&cnt[bin], 1);
    if (pos < BIN_CAP)
        entries[((size_t)bin << BUCKET_BITS) + pos] =
            (unsigned)in | ((unsigned)(o & (BUCKET_ROWS - 1)) << 17);
}

// ------------- main: block b walks all k-bins of bucket b; per tile:
// gather -> MFMA -> LDS repack -> fp16 pk-atomic scatter (R6 epilogue).
// All writes to bucket b's rows come from this one block -> L2-merged.
__global__ __launch_bounds__(256)
void k_bucket(const bf16_t* __restrict__ fb, const bf16_t* __restrict__ wp,
              const int* __restrict__ cnt, const unsigned* __restrict__ entries,
              __half* __restrict__ acc, int NB, int K3)
{
    __shared__ float scratch[4][16 * ROW_STRIDE];

    const int tid  = threadIdx.x;
    const int wave = tid >> 6;
    const int lane = tid & 63;
    const int quad = lane >> 4;
    const int col  = lane & 15;
    const int sub  = lane >> 5;   // 0/1: which of 2 rows in the pk-atomic loop
    const int c2   = lane & 31;   // half2 column index
    const int b    = blockIdx.x;
    const int row0 = b << BUCKET_BITS;
    float* ls = &scratch[wave][0];

    int tctr = 0;   // running tile counter for round-robin wave assignment
    for (int k = 0; k < K3; ++k) {
        int bin = k * NB + b;
        int n = min(cnt[bin], BIN_CAP);
        int ntile = (n + 15) >> 4;
        if (ntile == 0) continue;
        int rel = (wave - tctr) & 3;   // 4 waves; &3 == mod 4 (two's compl.)
        tctr += ntile;
        if (rel >= ntile) continue;

        // per-lane B fragments for this k (221KB table, L2-hot)
        const bf16_t* wpk = wp + ((size_t)(k * 64 + lane)) * 64;
        bf16x8 bf[2][4];
        #pragma unroll
        for (int ks = 0; ks < 2; ++ks)
            #pragma unroll
            for (int nt = 0; nt < 4; ++nt)
                bf[ks][nt] = *(const bf16x8*)(wpk + (ks * 4 + nt) * 8);

        const unsigned* ebase = entries + ((size_t)bin << BUCKET_BITS);
        for (int t = rel; t < ntile; t += 4) {
            int tbase = t * 16;
            // entry tbase+col, replicated across the 4 quads
            unsigned eown = ebase[min(tbase + col, n - 1)];
            int in      = (int)(eown & 0x1FFFFu);
            int out_idx = row0 + (int)((eown >> 17) & (BUCKET_ROWS - 1));

            // gather A fragments (R6 pattern): lane loads 16B at quad*8
            // and +32 rows of the bf16 feature row.
            const bf16_t* src = fb + ((size_t)in << 6) + quad * 8;
            bf16x8 a0 = *(const bf16x8*)(src);
            bf16x8 a1 = *(const bf16x8*)(src + 32);

            floatx4 c0 = {0.f,0.f,0.f,0.f}, c1 = {0.f,0.f,0.f,0.f};
            floatx4 c2v = {0.f,0.f,0.f,0.f}, c3 = {0.f,0.f,0.f,0.f};
            c0  = __builtin_amdgcn_mfma_f32_16x16x32_bf16(a0, bf[0][0], c0, 0, 0, 0);
            c0  = __builtin_amdgcn_mfma_f32_16x16x32_bf16(a1, bf[1][0], c0, 0, 0, 0);
            c1  = __builtin_amdgcn_mfma_f32_16x16x32_bf16(a0, bf[0][1], c1, 0, 0, 0);
            c1  = __builtin_amdgcn_mfma_f32_16x16x32_bf16(a1, bf[1][1], c1, 0, 0, 0);
            c2v = __builtin_amdgcn_mfma_f32_16x16x32_bf16(a0, bf[0][2], c2v, 0, 0, 0);
            c2v = __builtin_amdgcn_mfma_f32_16x16x32_bf16(a1, bf[1][2], c2v, 0, 0, 0);
            c3  = __builtin_amdgcn_mfma_f32_16x16x32_bf16(a0, bf[0][3], c3, 0, 0, 0);
            c3  = __builtin_amdgcn_mfma_f32_16x16x32_bf16(a1, bf[1][3], c3, 0, 0, 0);

            // Repack C tile into per-wave LDS (R6): ls[m][ch], m=quad*4+r.
            #pragma unroll
            for (int r = 0; r < 4; ++r) {
                int m = quad * 4 + r;
                ls[m * ROW_STRIDE + col +  0] = c0[r];
                ls[m * ROW_STRIDE + col + 16] = c1[r];
                ls[m * ROW_STRIDE + col + 32] = c2v[r];
                ls[m * ROW_STRIDE + col + 48] = c3[r];
            }
            asm volatile("s_waitcnt lgkmcnt(0)" ::: "memory");

            // fp16 packed atomics: 2 rows/instr, 32 half2 per row (R6).
            // Per row: 128B contiguous = 4 full 32B sectors.
            #pragma unroll
            for (int m2 = 0; m2 < 8; ++m2) {
                int m = m2 * 2 + sub;
                float2 v = *(const float2*)&ls[m * ROW_STRIDE + 2 * c2];
                __half2 h = __floats2half2_rn(v.x, v.y);
                int g = __shfl(out_idx, m);
                if (tbase + m < n)
                    unsafeAtomicAdd((__half2*)(acc + (size_t)g * C_DIM + 2 * c2), h);
            }
        }
    }
}

// ---------------------- per-channel sum / sumsq over the fp16 accumulator
__global__ __launch_bounds__(256)
void k2_stats_h(const __half* __restrict__ acc, float* __restrict__ sums,
                int n_rows)
{
    const int tid = threadIdx.x;
    const int c8  = tid & 7;    // channel octet
    const int sub = tid >> 3;   // 32 rows per block pass

    float s[8] = {0,0,0,0,0,0,0,0}, q[8] = {0,0,0,0,0,0,0,0};
    for (int r = blockIdx.x * 32 + sub; r < n_rows; r += gridDim.x * 32) {
        float4 v = *(const float4*)&acc[(size_t)r * C_DIM + c8 * 8];
        const __half2* h = (const __half2*)&v;
        #pragma unroll
        for (int j = 0; j < 4; ++j) {
            float x = __half2float(h[j].x), y = __half2float(h[j].y);
            s[2*j]   += x; q[2*j]   += x * x;
            s[2*j+1] += y; q[2*j+1] += y * y;
        }
    }

    __shared__ float red[128];
    if (tid < 128) red[tid] = 0.f;
    __syncthreads();
    #pragma unroll
    for (int j = 0; j < 8; ++j) {
        atomicAdd(&red[c8 * 8 + j], s[j]);
        atomicAdd(&red[64 + c8 * 8 + j], q[j]);
    }
    __syncthreads();
    if (tid < 128) atomicAdd(&sums[tid], red[tid]);
}

// ------------------------- BN normalize + ReLU: fp16 acc -> fp32 out
__global__ __launch_bounds__(256)
void k3_bn_relu_h(const __half* __restrict__ acc, float* __restrict__ out,
                  const float* __restrict__ sums,
                  const float* __restrict__ gamma, const float* __restrict__ beta,
                  int n_rows)
{
    int tid = blockIdx.x * 256 + threadIdx.x;
    int c8  = tid & 7;                   // fixed channel octet per thread
    float inv_n = 1.0f / (float)n_rows;

    float sc[8], sh[8];
    #pragma unroll
    for (int j = 0; j < 8; ++j) {
        int ch    = c8 * 8 + j;
        float m   = sums[ch] * inv_n;
        float var = sums[64 + ch] * inv_n - m * m;
        float inv = rsqrtf(var + 1e-5f);
        float g   = gamma[ch] * inv;
        sc[j] = g;
        sh[j] = beta[ch] - m * g;
    }

    size_t total = (size_t)n_rows * 8;   // halfx8 octets
    for (size_t i = tid; i < total; i += (size_t)gridDim.x * 256) {
        float4 v = ((const float4*)acc)[i];
        const __half2* h = (const __half2*)&v;
        float4 o0, o1;
        o0.x = fmaxf(__half2float(h[0].x) * sc[0] + sh[0], 0.f);
        o0.y = fmaxf(__half2float(h[0].y) * sc[1] + sh[1], 0.f);
        o0.z = fmaxf(__half2float(h[1].x) * sc[2] + sh[2], 0.f);
        o0.w = fmaxf(__half2float(h[1].y) * sc[3] + sh[3], 0.f);
        o1.x = fmaxf(__half2float(h[2].x) * sc[4] + sh[4], 0.f);
        o1.y = fmaxf(__half2float(h[2].y) * sc[5] + sh[5], 0.f);
        o1.z = fmaxf(__half2float(h[3].x) * sc[6] + sh[6], 0.f);
        o1.w = fmaxf(__half2float(h[3].y) * sc[7] + sh[7], 0.f);
        ((float4*)out)[2 * i]     = o0;
        ((float4*)out)[2 * i + 1] = o1;
    }
}

// ======================= R6 main kernel (proven fallback) ===================
__global__ __launch_bounds__(256)
void k1_fp16(const float* __restrict__ features,
             const bf16_t* __restrict__ fbf16,
             const float* __restrict__ weight,
             const int* __restrict__ pairs_in,
             const int* __restrict__ pairs_out,
             __half* __restrict__ acc,
             int P, int rows_per_block, int use_bf16)
{
    __shared__ bf16_t Wt[C_DIM * LDS_STRIDE];
    __shared__ float  scratch[4][16 * ROW_STRIDE];

    const int k   = blockIdx.y;
    const int tid = threadIdx.x;

    const float* Wk = weight + (size_t)k * C_DIM * C_DIM;
    for (int i = tid; i < C_DIM * C_DIM; i += 256) {
        int c = i >> 6, d = i & 63;
        Wt[d * LDS_STRIDE + c] = (bf16_t)Wk[i];
    }
    __syncthreads();

    const int wave = tid >> 6;
    const int lane = tid & 63;
    const int quad = lane >> 4;
    const int col  = lane & 15;
    const int sub  = lane >> 5;
    const int c2   = lane & 31;
    float* ls = &scratch[wave][0];

    bf16x8 bfrag[2][4];
    #pragma unroll
    for (int ks = 0; ks < 2; ++ks)
        #pragma unroll
        for (int nt = 0; nt < 4; ++nt)
            bfrag[ks][nt] =
                *(const bf16x8*)&Wt[(col + 16 * nt) * LDS_STRIDE + quad * 8 + 32 * ks];

    const int* __restrict__ pin  = pairs_in  + (size_t)k * P;
    const int* __restrict__ pout = pairs_out + (size_t)k * P;

    const int p0   = blockIdx.x * rows_per_block;
    const int pend = min(p0 + rows_per_block, P);

    for (int base = p0 + wave * 16; base < pend; base += 64) {
        int prow    = base + col;
        int clamped = (prow < pend) ? prow : (pend - 1);
        int in_idx  = pin[clamped];
        int out_idx = pout[clamped];

        bf16x8 a0, a1;
        if (use_bf16) {
            const bf16_t* src = fbf16 + (size_t)in_idx * C_DIM + quad * 8;
            a0 = *(const bf16x8*)(src);
            a1 = *(const bf16x8*)(src + 32);
        } else {
            const float* src = features + (size_t)in_idx * C_DIM + quad * 8;
            float4 f0 = *(const float4*)(src);
            float4 f1 = *(const float4*)(src + 4);
            float4 f2 = *(const float4*)(src + 32);
            float4 f3 = *(const float4*)(src + 36);
            a0[0] = (bf16_t)f0.x; a0[1] = (bf16_t)f0.y; a0[2] = (bf16_t)f0.z; a0[3] = (bf16_t)f0.w;
            a0[4] = (bf16_t)f1.x; a0[5] = (bf16_t)f1.y; a0[6] = (bf16_t)f1.z; a0[7] = (bf16_t)f1.w;
            a1[0] = (bf16_t)f2.x; a1[1] = (bf16_t)f2.y; a1[2] = (bf16_t)f2.z; a1[3] = (bf16_t)f2.w;
            a1[4] = (bf16_t)f3.x; a1[5] = (bf16_t)f3.y; a1[6] = (bf16_t)f3.z; a1[7] = (bf16_t)f3.w;
        }

        floatx4 acc0 = {0.f, 0.f, 0.f, 0.f};
        floatx4 acc1 = {0.f, 0.f, 0.f, 0.f};
        floatx4 acc2 = {0.f, 0.f, 0.f, 0.f};
        floatx4 acc3 = {0.f, 0.f, 0.f, 0.f};

        acc0 = __builtin_amdgcn_mfma_f32_16x16x32_bf16(a0, bfrag[0][0], acc0, 0, 0, 0);
        acc0 = __builtin_amdgcn_mfma_f32_16x16x32_bf16(a1, bfrag[1][0], acc0, 0, 0, 0);
        acc1 = __builtin_amdgcn_mfma_f32_16x16x32_bf16(a0, bfrag[0][1], acc1, 0, 0, 0);
        acc1 = __builtin_amdgcn_mfma_f32_16x16x32_bf16(a1, bfrag[1][1], acc1, 0, 0, 0);
        acc2 = __builtin_amdgcn_mfma_f32_16x16x32_bf16(a0, bfrag[0][2], acc2, 0, 0, 0);
        acc2 = __builtin_amdgcn_mfma_f32_16x16x32_bf16(a1, bfrag[1][2], acc2, 0, 0, 0);
        acc3 = __builtin_amdgcn_mfma_f32_16x16x32_bf16(a0, bfrag[0][3], acc3, 0, 0, 0);
        acc3 = __builtin_amdgcn_mfma_f32_16x16x32_bf16(a1, bfrag[1][3], acc3, 0, 0, 0);

        #pragma unroll
        for (int r = 0; r < 4; ++r) {
            int m = quad * 4 + r;
            ls[m * ROW_STRIDE + col +  0] = acc0[r];
            ls[m * ROW_STRIDE + col + 16] = acc1[r];
            ls[m * ROW_STRIDE + col + 32] = acc2[r];
            ls[m * ROW_STRIDE + col + 48] = acc3[r];
        }
        asm volatile("s_waitcnt lgkmcnt(0)" ::: "memory");

        #pragma unroll
        for (int m2 = 0; m2 < 8; ++m2) {
            int m = m2 * 2 + sub;
            float2 v = *(const float2*)&ls[m * ROW_STRIDE + 2 * c2];
            __half2 h = __floats2half2_rn(v.x, v.y);
            int g = __shfl(out_idx, m);
            if (base + m < pend)
                unsafeAtomicAdd((__half2*)(acc + (size_t)g * C_DIM + 2 * c2), h);
        }
    }
}

// ===================== fallback (R1 path, proven) ===========================
__global__ __launch_bounds__(256)
void k1_scatter_gemm(const float* __restrict__ features,
                     const float* __restrict__ weight,
                     const int* __restrict__ pairs_in,
                     const int* __restrict__ pairs_out,
                     float* __restrict__ out,
                     int P, int rows_per_block)
{
    __shared__ bf16_t Wt[C_DIM * LDS_STRIDE];
    const int k   = blockIdx.y;
    const int tid = threadIdx.x;
    const float* Wk = weight + (size_t)k * C_DIM * C_DIM;
    for (int i = tid; i < C_DIM * C_DIM; i += 256) {
        int c = i >> 6, d = i & 63;
        Wt[d * LDS_STRIDE + c] = (bf16_t)Wk[i];
    }
    __syncthreads();
    const int wave = tid >> 6, lane = tid & 63, quad = lane >> 4, col = lane & 15;
    bf16x8 bfrag[2][4];
    #pragma unroll
    for (int ks = 0; ks < 2; ++ks)
        #pragma unroll
        for (int nt = 0; nt < 4; ++nt)
            bfrag[ks][nt] =
                *(const bf16x8*)&Wt[(col + 16 * nt) * LDS_STRIDE + quad * 8 + 32 * ks];
    const int* __restrict__ pin  = pairs_in  + (size_t)k * P;
    const int* __restrict__ pout = pairs_out + (size_t)k * P;
    const int p0   = blockIdx.x * rows_per_block;
    const int pend = min(p0 + rows_per_block, P);
    for (int base = p0 + wave * 16; base < pend; base += 64) {
        int prow    = base + col;
        int clamped = (prow < pend) ? prow : (pend - 1);
        int in_idx  = pin[clamped];
        int out_idx = pout[clamped];
        const float* src = features + (size_t)in_idx * C_DIM + quad * 8;
        float4 f0 = *(const float4*)(src);
        float4 f1 = *(const float4*)(src + 4);
        float4 f2 = *(const float4*)(src + 32);
        float4 f3 = *(const float4*)(src + 36);
        bf16x8 a0, a1;
        a0[0] = (bf16_t)f0.x; a0[1] = (bf16_t)f0.y; a0[2] = (bf16_t)f0.z; a0[3] = (bf16_t)f0.w;
        a0[4] = (bf16_t)f1.x; a0[5] = (bf16_t)f1.y; a0[6] = (bf16_t)f1.z; a0[7] = (bf16_t)f1.w;
        a1[0] = (bf16_t)f2.x; a1[1] = (bf16_t)f2.y; a1[2] = (bf16_t)f2.z; a1[3] = (bf16_t)f2.w;
        a1[4] = (bf16_t)f3.x; a1[5] = (bf16_t)f3.y; a1[6] = (bf16_t)f3.z; a1[7] = (bf16_t)f3.w;
        floatx4 acc0 = {0.f,0.f,0.f,0.f}, acc1 = {0.f,0.f,0.f,0.f};
        floatx4 acc2 = {0.f,0.f,0.f,0.f}, acc3 = {0.f,0.f,0.f,0.f};
        acc0 = __builtin_amdgcn_mfma_f32_16x16x32_bf16(a0, bfrag[0][0], acc0, 0, 0, 0);
        acc0 = __builtin_amdgcn_mfma_f32_16x16x32_bf16(a1, bfrag[1][0], acc0, 0, 0, 0);
        acc1 = __builtin_amdgcn_mfma_f32_16x16x32_bf16(a0, bfrag[0][1], acc1, 0, 0, 0);
        acc1 = __builtin_amdgcn_mfma_f32_16x16x32_bf16(a1, bfrag[1][1], acc1, 0, 0, 0);
        acc2 = __builtin_amdgcn_mfma_f32_16x16x32_bf16(a0, bfrag[0][2], acc2, 0, 0, 0);
        acc2 = __builtin_amdgcn_mfma_f32_16x16x32_bf16(a1, bfrag[1][2], acc2, 0, 0, 0);
        acc3 = __builtin_amdgcn_mfma_f32_16x16x32_bf16(a0, bfrag[0][3], acc3, 0, 0, 0);
        acc3 = __builtin_amdgcn_mfma_f32_16x16x32_bf16(a1, bfrag[1][3], acc3, 0, 0, 0);
        #pragma unroll
        for (int r = 0; r < 4; ++r) {
            int m = quad * 4 + r;
            int g = __shfl(out_idx, m);
            if (base + m < pend) {
                float* dst = out + (size_t)g * C_DIM + col;
                unsafeAtomicAdd(dst +  0, acc0[r]);
                unsafeAtomicAdd(dst + 16, acc1[r]);
                unsafeAtomicAdd(dst + 32, acc2[r]);
                unsafeAtomicAdd(dst + 48, acc3[r]);
            }
        }
    }
}

__global__ __launch_bounds__(256)
void k2_stats(const float* __restrict__ acc, float* __restrict__ sums, int n_rows)
{
    int tid = threadIdx.x;
    int ch  = tid & 63;
    int sub = tid >> 6;
    float s = 0.f, s2 = 0.f;
    for (int r = blockIdx.x * 4 + sub; r < n_rows; r += gridDim.x * 4) {
        float v = acc[(size_t)r * C_DIM + ch];
        s  += v;
        s2 += v * v;
    }
    __shared__ float red[256];
    red[tid] = s;
    __syncthreads();
    if (tid < 64) {
        float t = red[tid] + red[tid + 64] + red[tid + 128] + red[tid + 192];
        atomicAdd(&sums[ch], t);
    }
    __syncthreads();
    red[tid] = s2;
    __syncthreads();
    if (tid < 64) {
        float t = red[tid] + red[tid + 64] + red[tid + 128] + red[tid + 192];
        atomicAdd(&sums[64 + ch], t);
    }
}

__global__ __launch_bounds__(256)
void k3_bn_relu(float* __restrict__ out, const float* __restrict__ sums,
                const float* __restrict__ gamma, const float* __restrict__ beta,
                int n_rows)
{
    int tid = blockIdx.x * 256 + threadIdx.x;
    int ch0 = (tid * 4) & 63;
    float inv_n = 1.0f / (float)n_rows;
    float sc[4], sh[4];
    #pragma unroll
    for (int j = 0; j < 4; ++j) {
        int ch    = ch0 + j;
        float m   = sums[ch] * inv_n;
        float var = sums[64 + ch] * inv_n - m * m;
        float inv = rsqrtf(var + 1e-5f);
        float g   = gamma[ch] * inv;
        sc[j] = g;
        sh[j] = beta[ch] - m * g;
    }
    size_t total = (size_t)n_rows * C_DIM / 4;
    for (size_t i = tid; i < total; i += (size_t)gridDim.x * 256) {
        float4 v = ((const float4*)out)[i];
        v.x = fmaxf(v.x * sc[0] + sh[0], 0.f);
        v.y = fmaxf(v.y * sc[1] + sh[1], 0.f);
        v.z = fmaxf(v.z * sc[2] + sh[2], 0.f);
        v.w = fmaxf(v.w * sc[3] + sh[3], 0.f);
        ((float4*)out)[i] = v;
    }
}

// ============================================================================
extern "C" void kernel_launch(void* const* d_in, const int* in_sizes, int n_in,
                              void* d_out, int out_size, void* d_ws, size_t ws_size,
                              hipStream_t stream)
{
    const float* features  = (const float*)d_in[0];
    const float* weight    = (const float*)d_in[1];
    // d_in[2] = bias (cancels in training-mode BN)
    const float* gamma     = (const float*)d_in[3];
    const float* beta      = (const float*)d_in[4];
    const int*   pairs_in  = (const int*)d_in[5];
    const int*   pairs_out = (const int*)d_in[6];

    const int n_out     = out_size / C_DIM;
    const int n_in_rows = in_sizes[0] / C_DIM;
    const int K3        = in_sizes[1] / (C_DIM * C_DIM);
    const int P         = in_sizes[5] / K3;

    float* out = (float*)d_out;

    // -------- clustered path workspace: sums | cnt | acc(fp16) | fb | wp | entries
    const int    NB      = (n_out + BUCKET_ROWS - 1) >> BUCKET_BITS;
    const size_t NBINS   = (size_t)K3 * NB;
    const size_t off_cnt = 512;
    const size_t off_acc = (off_cnt + NBINS * 4 + 255) & ~(size_t)255;
    const size_t acc_bytes = (size_t)n_out * C_DIM * 2;
    const size_t off_fb  = (off_acc + acc_bytes + 255) & ~(size_t)255;
    const size_t fb_bytes = (size_t)n_in_rows * C_DIM * 2;
    const size_t off_wp  = (off_fb + fb_bytes + 255) & ~(size_t)255;
    const size_t off_en  = (off_wp + (size_t)K3 * C_DIM * C_DIM * 2 + 255) & ~(size_t)255;
    const size_t need_c  = off_en + NBINS * BIN_CAP * 4;

    if (ws_size >= need_c && n_in_rows <= (1 << 17)) {
        float*    sums  = (float*)d_ws;
        int*      cnt   = (int*)((char*)d_ws + off_cnt);
        __half*   acc   = (__half*)((char*)d_ws + off_acc);
        bf16_t*   fb    = (bf16_t*)((char*)d_ws + off_fb);
        bf16_t*   wpb   = (bf16_t*)((char*)d_ws + off_wp);
        unsigned* ent   = (unsigned*)((char*)d_ws + off_en);

        // single fused clear: sums + cnt + fp16 accumulator (contiguous)
        hipMemsetAsync(d_ws, 0, off_acc + acc_bytes, stream);
        k_fprep<<<(n_in_rows * 16 + 255) / 256, 256, 0, stream>>>(
            features, fb, n_in_rows * 16);
        w_prep<<<K3, 64, 0, stream>>>(weight, wpb);

        dim3 gr((P + 255) / 256, K3);
        b_reorder<<<gr, 256, 0, stream>>>(pairs_in, pairs_out, cnt, ent, P, NB);

        k_bucket<<<NB, 256, 0, stream>>>(fb, wpb, cnt, ent, acc, NB, K3);

        k2_stats_h<<<dim3(256), 256, 0, stream>>>(acc, sums, n_out);
        k3_bn_relu_h<<<dim3(512), 256, 0, stream>>>(acc, out, sums, gamma,
                                                    beta, n_out);
        return;
    }

    // ---------------- R6 fp16-atomic path (proven fallback) ----------------
    size_t acc_bytes6 = (size_t)n_out * C_DIM * 2;
    size_t off_acc6   = 512;
    size_t off_fb6    = (off_acc6 + acc_bytes6 + 255) & ~(size_t)255;
    size_t fb_bytes6  = (size_t)n_in_rows * C_DIM * 2;
    size_t need_b     = off_acc6 + acc_bytes6;
    size_t need_a     = off_fb6 + fb_bytes6;

    float*  sums  = (float*)d_ws;
    __half* acc   = (__half*)((char*)d_ws + off_acc6);
    bf16_t* fbf16 = (bf16_t*)((char*)d_ws + off_fb6);

    const int rows_per_block = 512;
    dim3 g1((P + rows_per_block - 1) / rows_per_block, K3);

    if (ws_size >= need_b) {
        const int use_bf16 = (ws_size >= need_a) ? 1 : 0;

        hipMemsetAsync(d_ws, 0, off_acc6 + acc_bytes6, stream);
        if (use_bf16)
            k_fprep<<<(n_in_rows * 16 + 255) / 256, 256, 0, stream>>>(
                features, fbf16, n_in_rows * 16);

        k1_fp16<<<g1, 256, 0, stream>>>(features, fbf16, weight, pairs_in,
                                        pairs_out, acc, P, rows_per_block,
                                        use_bf16);

        k2_stats_h<<<dim3(256), 256, 0, stream>>>(acc, sums, n_out);
        k3_bn_relu_h<<<dim3(512), 256, 0, stream>>>(acc, out, sums, gamma,
                                                    beta, n_out);
    } else {
        hipMemsetAsync(d_out, 0, (size_t)out_size * sizeof(float), stream);
        hipMemsetAsync(d_ws, 0, 512, stream);

        k1_scatter_gemm<<<g1, 256, 0, stream>>>(features, weight, pairs_in,
                                                pairs_out, out, P, rows_per_block);
        k2_stats<<<dim3(1024), 256, 0, stream>>>(out, sums, n_out);
        k3_bn_relu<<<dim3(1024), 256, 0, stream>>>(out, sums, gamma, beta, n_out);
    }
}